// Round 3
// baseline (80.423 us; speedup 1.0000x reference)
//
#include <hip/hip_runtime.h>

#define THREADS 256
#define PB 7                 // puzzles per block-iteration; 7*9=63 constraint lanes = 1 wave

__global__ __launch_bounds__(THREADS) void sudoku_main(
    const float* __restrict__ logits,
    const int*   __restrict__ targets,
    const int*   __restrict__ puzzles,
    float* __restrict__ acc,
    int B)
{
  __shared__ float probT[PB * 9 * 81];   // class-major masked probs (20412 B)
  __shared__ float sred[4][5];

  const int tid = threadIdx.x;
  const int numGroups = (B + PB - 1) / PB;

  float a_focal = 0.f, a_ent = 0.f, a_msk = 0.f, a_uniq = 0.f, a_sq = 0.f;

  for (int g = blockIdx.x; g < numGroups; g += gridDim.x) {
    const int grp = min(PB, B - g * PB);          // puzzles in this group

    // ---- phase A: per-cell softmax / focal / entropy / top-2 ----
    // direct global loads (9 dwords/lane, wave covers 2304B contiguous)
#pragma unroll
    for (int r = 0; r < (PB * 81 + THREADS - 1) / THREADS; ++r) {
      int c = tid + r * THREADS;
      if (c < grp * 81) {
        int lp   = c / 81;
        int cell = c - lp * 81;
        const size_t cidx = (size_t)g * (PB * 81) + c;
        const float* Lp = logits + cidx * 9;
        float l[9];
#pragma unroll
        for (int i = 0; i < 9; ++i) l[i] = Lp[i];
        int tg = targets[cidx] - 1;
        int pz = puzzles[cidx];
        tg = tg < 0 ? 0 : (tg > 8 ? 8 : tg);

        float m = l[0];
#pragma unroll
        for (int i = 1; i < 9; ++i) m = fmaxf(m, l[i]);
        float e[9], s = 0.f, lsum = 0.f, e1 = -1.f, e2 = -1.f;
#pragma unroll
        for (int i = 0; i < 9; ++i) {
          float x  = l[i] - m;
          float ei = __expf(x);
          e[i] = ei;
          s += ei;
          lsum += ei * x;
          if (ei > e1) { e2 = e1; e1 = ei; }
          else if (ei > e2) { e2 = ei; }
        }
        float inv_s = 1.f / s;
        float logs  = __logf(s);

        float lpt   = (l[tg] - m) - logs;       // log p_target
        float pt    = e[tg] * inv_s;
        float om    = 1.f - pt;
        float focal = om * om * (-lpt);

        float ent = logs - lsum * inv_s;        // -(sum p*log p)
        float gap = (e1 - e2) * inv_s;
        float uq  = fmaxf(0.f, 1.f - gap);

        float mk = (pz == 0) ? 1.f : 0.f;
        a_focal += focal * mk;
        a_ent   += ent * mk;
        a_msk   += mk;
        a_uniq  += uq;                          // uniqueness is unmasked

        float pm = inv_s * mk;
        // class-major store: lanes consecutive in `cell` -> stride-1 words, conflict-free
#pragma unroll
        for (int i = 0; i < 9; ++i) probT[(lp * 9 + i) * 81 + cell] = e[i] * pm;
      }
    }
    __syncthreads();

    // ---- phase C: one thread per (puzzle, class); 81 b32 reads, 27 sums in regs ----
    if (tid < grp * 9) {
      const int base = tid * 81;                // == (lp*9+cls)*81 ; 81%32=17 odd -> no conflicts
      float rs[9], cs[9], bs[9];
#pragma unroll
      for (int u = 0; u < 9; ++u) { rs[u] = 0.f; cs[u] = 0.f; bs[u] = 0.f; }
#pragma unroll
      for (int k = 0; k < 81; ++k) {
        float v = probT[base + k];
        rs[k / 9]                    += v;      // row (sum over axis 2)
        cs[k % 9]                    += v;      // col (sum over axis 1)
        bs[(k / 27) * 3 + (k % 9) / 3] += v;    // 3x3 box
      }
#pragma unroll
      for (int u = 0; u < 9; ++u) {
        float dr = rs[u] - 1.f, dc = cs[u] - 1.f, db = bs[u] - 1.f;
        a_sq += dr * dr + dc * dc + db * db;
      }
    }
    __syncthreads();
  }

  // ---- wave (64-lane) + block reduction, one atomicAdd set per block ----
#pragma unroll
  for (int off = 32; off > 0; off >>= 1) {
    a_focal += __shfl_down(a_focal, off);
    a_ent   += __shfl_down(a_ent,   off);
    a_msk   += __shfl_down(a_msk,   off);
    a_uniq  += __shfl_down(a_uniq,  off);
    a_sq    += __shfl_down(a_sq,    off);
  }
  const int wave = tid >> 6;
  if ((tid & 63) == 0) {
    sred[wave][0] = a_focal; sred[wave][1] = a_ent; sred[wave][2] = a_msk;
    sred[wave][3] = a_uniq;  sred[wave][4] = a_sq;
  }
  __syncthreads();
  if (tid < 5) {
    float v = sred[0][tid] + sred[1][tid] + sred[2][tid] + sred[3][tid];
    atomicAdd(&acc[tid], v);
  }
}

__global__ void sudoku_finalize(const float* __restrict__ acc,
                                float* __restrict__ out, float invBG)
{
  float focal = acc[0], ent = acc[1], msum = acc[2], uniq = acc[3], sq = acc[4];
  float inv_m = 1.f / (msum + 1e-8f);
  float ce    = focal * inv_m;
  float entl  = 0.1f * ent * inv_m;
  float uql   = 0.1f * uniq * invBG;
  float rcb   = sq * invBG;    // (row+col+box) means share denominator B*81
  float constraint = (rcb + entl + uql) * 0.2f;
  out[0] = ce + 0.5f * constraint;
}

extern "C" void kernel_launch(void* const* d_in, const int* in_sizes, int n_in,
                              void* d_out, int out_size, void* d_ws, size_t ws_size,
                              hipStream_t stream)
{
  (void)n_in; (void)out_size; (void)ws_size;
  const float* logits  = (const float*)d_in[0];
  const int*   targets = (const int*)d_in[1];
  const int*   puzzles = (const int*)d_in[2];
  float* out = (float*)d_out;
  float* acc = (float*)d_ws;

  const int B = in_sizes[0] / 729;            // B*9*9*9 logits
  const int numGroups = (B + PB - 1) / PB;

  hipMemsetAsync(acc, 0, 5 * sizeof(float), stream);

  int grid = numGroups < 2048 ? numGroups : 2048;
  sudoku_main<<<grid, THREADS, 0, stream>>>(logits, targets, puzzles, acc, B);

  const float invBG = 1.f / ((float)B * 81.f);
  sudoku_finalize<<<1, 1, 0, stream>>>(acc, out, invBG);
}

// Round 4
// 68.772 us; speedup vs baseline: 1.1694x; 1.1694x over previous
//
#include <hip/hip_runtime.h>

#define THREADS 256
#define PB 3                   // puzzles per block-iteration; 243 phase-A workers
#define ROWW 84                // padded row width (words) so 81-float rows are 16B-phase-aligned

typedef float f4 __attribute__((ext_vector_type(4)));
typedef f4 f4u __attribute__((aligned(4)));      // 4B-aligned float4 loads (HW allows dword align)

__global__ __launch_bounds__(THREADS) void sudoku_main(
    const float* __restrict__ logits,
    const int*   __restrict__ targets,
    const int*   __restrict__ puzzles,
    float* __restrict__ acc,
    int B)
{
  __shared__ float probT[PB * 9 * ROWW];   // class-major masked probs, padded (9072 B)
  __shared__ float sred[4][5];

  const int tid  = threadIdx.x;
  const int lp   = tid / 81;               // phase-A local puzzle (workers only)
  const int cell = tid % 81;
  const bool workerA = tid < 243;
  const int cp   = tid / 9;                // phase-C local puzzle (tid<27)
  const int numGroups = (B + PB - 1) / PB;

  float a_focal = 0.f, a_ent = 0.f, a_msk = 0.f, a_uniq = 0.f, a_sq = 0.f;

  for (int g = blockIdx.x; g < numGroups; g += gridDim.x) {
    const int grp = min(PB, B - g * PB);

    // ---- phase A: one cell per thread, everything in registers ----
    if (workerA && lp < grp) {
      const size_t cidx = (size_t)g * (PB * 81) + tid;   // tid == lp*81+cell
      const float* Lp = logits + cidx * 9;
      f4 v0 = *(const f4u*)(Lp);
      f4 v1 = *(const f4u*)(Lp + 4);
      float l8 = Lp[8];
      int tg = targets[cidx] - 1;
      int pz = puzzles[cidx];
      tg = tg < 0 ? 0 : (tg > 8 ? 8 : tg);

      float l[9];
      l[0]=v0[0]; l[1]=v0[1]; l[2]=v0[2]; l[3]=v0[3];
      l[4]=v1[0]; l[5]=v1[1]; l[6]=v1[2]; l[7]=v1[3]; l[8]=l8;

      // branchless top-2 of the LOGITS (exp is monotone)
      float t1 = l[0], t2 = -3.0e38f;
#pragma unroll
      for (int i = 1; i < 9; ++i) {
        float hi = fmaxf(t1, l[i]);
        float lo = fminf(t1, l[i]);
        t1 = hi;
        t2 = fmaxf(t2, lo);
      }

      float e[9], s = 0.f, lsum = 0.f, ltg = l[0];
#pragma unroll
      for (int i = 0; i < 9; ++i) {
        float x  = l[i] - t1;
        float ei = __expf(x);
        e[i] = ei;
        s += ei;
        lsum = fmaf(ei, x, lsum);
        if (i > 0) ltg = (tg == i) ? l[i] : ltg;   // static-index selects, no reg-array indexing
      }
      float inv_s = __builtin_amdgcn_rcpf(s);
      float logs  = __logf(s);

      float lpt   = (ltg - t1) - logs;         // log p_target  (<= 0)
      float pt    = __expf(lpt);
      float om    = 1.f - pt;
      float focal = om * om * (-lpt);

      float ent = logs - lsum * inv_s;         // -(sum p*log p)
      float gap = (1.f - __expf(t2 - t1)) * inv_s;   // (p1 - p2)
      float uq  = fmaxf(0.f, 1.f - gap);

      float mk = (pz == 0) ? 1.f : 0.f;
      a_focal += focal * mk;
      a_ent   += ent * mk;
      a_msk   += mk;
      a_uniq  += uq;                           // uniqueness is unmasked

      float pm = inv_s * mk;
#pragma unroll
      for (int i = 0; i < 9; ++i)
        probT[(lp * 9 + i) * ROWW + cell] = e[i] * pm;   // stride-1 across lanes: conflict-free
    }
    __syncthreads();

    // ---- phase C: one thread per (puzzle,class); 81 floats via ds_read_b128 ----
    if (tid < 27 && cp < grp) {
      const float* base = &probT[tid * ROWW];  // 336B-aligned -> b128-friendly
      float rs[9], cs[9], bs[9];
#pragma unroll
      for (int u = 0; u < 9; ++u) { rs[u] = 0.f; cs[u] = 0.f; bs[u] = 0.f; }
#pragma unroll
      for (int q = 0; q < 20; ++q) {           // 20 x float4 = 80
        f4 v = *(const f4*)(base + q * 4);
#pragma unroll
        for (int j = 0; j < 4; ++j) {
          const int k = q * 4 + j;
          float x = v[j];
          rs[k / 9] += x;
          cs[k % 9] += x;
          bs[(k / 27) * 3 + (k % 9) / 3] += x;
        }
      }
      {
        float x = base[80];                    // k = 80
        rs[8] += x; cs[8] += x; bs[8] += x;
      }
#pragma unroll
      for (int u = 0; u < 9; ++u) {
        float dr = rs[u] - 1.f, dc = cs[u] - 1.f, db = bs[u] - 1.f;
        a_sq = fmaf(dr, dr, a_sq);
        a_sq = fmaf(dc, dc, a_sq);
        a_sq = fmaf(db, db, a_sq);
      }
    }
    __syncthreads();
  }

  // ---- wave + block reduction, one atomicAdd set per block ----
#pragma unroll
  for (int off = 32; off > 0; off >>= 1) {
    a_focal += __shfl_down(a_focal, off);
    a_ent   += __shfl_down(a_ent,   off);
    a_msk   += __shfl_down(a_msk,   off);
    a_uniq  += __shfl_down(a_uniq,  off);
    a_sq    += __shfl_down(a_sq,    off);
  }
  const int wave = tid >> 6;
  if ((tid & 63) == 0) {
    sred[wave][0] = a_focal; sred[wave][1] = a_ent; sred[wave][2] = a_msk;
    sred[wave][3] = a_uniq;  sred[wave][4] = a_sq;
  }
  __syncthreads();
  if (tid < 5) {
    float v = sred[0][tid] + sred[1][tid] + sred[2][tid] + sred[3][tid];
    atomicAdd(&acc[tid], v);
  }
}

__global__ void sudoku_finalize(const float* __restrict__ acc,
                                float* __restrict__ out, float invBG)
{
  float focal = acc[0], ent = acc[1], msum = acc[2], uniq = acc[3], sq = acc[4];
  float inv_m = 1.f / (msum + 1e-8f);
  float ce    = focal * inv_m;
  float entl  = 0.1f * ent * inv_m;
  float uql   = 0.1f * uniq * invBG;
  float rcb   = sq * invBG;    // row+col+box means share denominator B*81
  float constraint = (rcb + entl + uql) * 0.2f;
  out[0] = ce + 0.5f * constraint;
}

extern "C" void kernel_launch(void* const* d_in, const int* in_sizes, int n_in,
                              void* d_out, int out_size, void* d_ws, size_t ws_size,
                              hipStream_t stream)
{
  (void)n_in; (void)out_size; (void)ws_size;
  const float* logits  = (const float*)d_in[0];
  const int*   targets = (const int*)d_in[1];
  const int*   puzzles = (const int*)d_in[2];
  float* out = (float*)d_out;
  float* acc = (float*)d_ws;

  const int B = in_sizes[0] / 729;             // B*9*9*9 logits
  const int numGroups = (B + PB - 1) / PB;

  hipMemsetAsync(acc, 0, 5 * sizeof(float), stream);

  int grid = numGroups < 2048 ? numGroups : 2048;
  sudoku_main<<<grid, THREADS, 0, stream>>>(logits, targets, puzzles, acc, B);

  const float invBG = 1.f / ((float)B * 81.f);
  sudoku_finalize<<<1, 1, 0, stream>>>(acc, out, invBG);
}

// Round 5
// 61.036 us; speedup vs baseline: 1.3176x; 1.1267x over previous
//
#include <hip/hip_runtime.h>

#define THREADS 256
#define PB 3                 // puzzles per block-iteration; 243 phase-A workers
#define COLW 84              // words per (puzzle,class) column = 3 bands x 28 (16B-aligned bands)

typedef float f4 __attribute__((ext_vector_type(4)));
typedef f4 f4a4 __attribute__((aligned(4)));   // dword-aligned float4 global loads

__global__ __launch_bounds__(THREADS) void sudoku_main(
    const float* __restrict__ logits,
    const int*   __restrict__ targets,
    const int*   __restrict__ puzzles,
    float* __restrict__ acc,
    int B)
{
  __shared__ float probT[2][PB * 9 * COLW];   // double-buffered class-major probs (18.1 KB)
  __shared__ float sred[4][5];

  const int tid  = threadIdx.x;
  const int lp   = tid / 81;                  // phase-A local puzzle
  const int cell = tid % 81;
  const bool workerA = tid < 243;
  const int cpad = 28 * (cell / 27) + (cell % 27);   // band-padded column offset
  const int B81  = B * 81;
  const int numGroups = (B + PB - 1) / PB;

  // phase-C mapping: wave w (0..2) = local puzzle; lanes 0..26 = (class, band)
  const int cw   = tid >> 6;
  const int l27  = tid & 63;
  const bool workerC = (l27 < 27) && (cw < 3);
  const int ccls = l27 / 3;
  const int ck   = l27 % 3;

  float a_focal = 0.f, a_ent = 0.f, a_msk = 0.f, a_uniq = 0.f, a_sq = 0.f;

  // ---- prefetch group 0 into registers ----
  int g0 = blockIdx.x;
  bool vA = workerA && (g0 < numGroups) && (g0 * 243 + tid < B81);
  f4 c0{}, c1{}; float c8 = 0.f; int ctg = 0, cpz = 0;
  if (vA) {
    const float* Lp = logits + (size_t)(g0 * 243 + tid) * 9;
    c0 = *(const f4a4*)Lp; c1 = *(const f4a4*)(Lp + 4); c8 = Lp[8];
    ctg = targets[g0 * 243 + tid]; cpz = puzzles[g0 * 243 + tid];
  }

  int it = 0;
  for (int g = blockIdx.x; g < numGroups; g += gridDim.x, ++it) {
    float* PT = probT[it & 1];

    // ---- phase A: compute from prefetched registers, write probs to LDS ----
    if (vA) {
      float l[9];
      l[0]=c0[0]; l[1]=c0[1]; l[2]=c0[2]; l[3]=c0[3];
      l[4]=c1[0]; l[5]=c1[1]; l[6]=c1[2]; l[7]=c1[3]; l[8]=c8;
      int tg = ctg - 1; tg = tg < 0 ? 0 : (tg > 8 ? 8 : tg);

      float t1 = l[0], t2 = -3.0e38f;          // branchless top-2 of logits
#pragma unroll
      for (int i = 1; i < 9; ++i) {
        float hi = fmaxf(t1, l[i]);
        float lo = fminf(t1, l[i]);
        t1 = hi;
        t2 = fmaxf(t2, lo);
      }
      float e[9], s = 0.f, lsum = 0.f, ltg = l[0];
#pragma unroll
      for (int i = 0; i < 9; ++i) {
        float x  = l[i] - t1;
        float ei = __expf(x);
        e[i] = ei;
        s += ei;
        lsum = fmaf(ei, x, lsum);
        if (i > 0) ltg = (tg == i) ? l[i] : ltg;
      }
      float inv_s = __builtin_amdgcn_rcpf(s);
      float logs  = __logf(s);
      float lpt   = (ltg - t1) - logs;
      float pt    = __expf(lpt);
      float om    = 1.f - pt;
      float focal = om * om * (-lpt);
      float ent   = logs - lsum * inv_s;
      float gap   = (1.f - __expf(t2 - t1)) * inv_s;
      float uq    = fmaxf(0.f, 1.f - gap);
      float mk    = (cpz == 0) ? 1.f : 0.f;
      a_focal += focal * mk;
      a_ent   += ent * mk;
      a_msk   += mk;
      a_uniq  += uq;                           // uniqueness is unmasked
      float pm = inv_s * mk;
#pragma unroll
      for (int i = 0; i < 9; ++i)
        PT[(lp * 9 + i) * COLW + cpad] = e[i] * pm;
    }

    // ---- prefetch group t+1 BEFORE the barrier (latency hides under C + A) ----
    const int gn = g + (int)gridDim.x;
    const bool vAn = workerA && (gn < numGroups) && (gn * 243 + tid < B81);
    f4 n0{}, n1{}; float n8 = 0.f; int ntg = 0, npz = 0;
    if (vAn) {
      const float* Lp = logits + (size_t)(gn * 243 + tid) * 9;
      n0 = *(const f4a4*)Lp; n1 = *(const f4a4*)(Lp + 4); n8 = Lp[8];
      ntg = targets[gn * 243 + tid]; npz = puzzles[gn * 243 + tid];
    }

    __syncthreads();   // the ONLY barrier per iteration (double-buffer makes 2nd unneeded)

    // ---- phase C: thread (puzzle=wave, class, band) reads 27 cells, sums in regs ----
    if (workerC && (g * PB + cw) < B) {
      const float* base = PT + (cw * 9 + ccls) * COLW + 28 * ck;   // 16B-aligned
      float vv[28];
      ((f4*)vv)[0] = *(const f4*)(base);
      ((f4*)vv)[1] = *(const f4*)(base + 4);
      ((f4*)vv)[2] = *(const f4*)(base + 8);
      ((f4*)vv)[3] = *(const f4*)(base + 12);
      ((f4*)vv)[4] = *(const f4*)(base + 16);
      ((f4*)vv)[5] = *(const f4*)(base + 20);
      ((f4*)vv)[6] = *(const f4*)(base + 24);  // word 27 is pad, ignored
      float rs[3] = {0.f,0.f,0.f}, bs[3] = {0.f,0.f,0.f};
      float cs[9] = {0.f,0.f,0.f,0.f,0.f,0.f,0.f,0.f,0.f};
#pragma unroll
      for (int j = 0; j < 27; ++j) {           // all indices compile-time after unroll
        float v = vv[j];
        rs[j / 9]       += v;                  // row 3*ck + j/9 (complete)
        cs[j % 9]       += v;                  // col partial (1 of 3 bands)
        bs[(j % 9) / 3] += v;                  // box (ck, (j%9)/3) (complete)
      }
#pragma unroll
      for (int r = 0; r < 3; ++r) {
        float d = rs[r] - 1.f; a_sq = fmaf(d, d, a_sq);
        d = bs[r] - 1.f;       a_sq = fmaf(d, d, a_sq);
      }
      float csq = 0.f;                         // col totals: combine 3 bands via shfl
#pragma unroll
      for (int c9 = 0; c9 < 9; ++c9) {
        float t = cs[c9] + __shfl_down(cs[c9], 1) + __shfl_down(cs[c9], 2);
        float d = t - 1.f;
        csq = fmaf(d, d, csq);                 // garbage on ck!=0 lanes, discarded below
      }
      if (ck == 0) a_sq += csq;
    }

    // rotate prefetched registers
    vA = vAn; c0 = n0; c1 = n1; c8 = n8; ctg = ntg; cpz = npz;
  }

  // ---- wave + block reduction, one atomicAdd set per block ----
#pragma unroll
  for (int off = 32; off > 0; off >>= 1) {
    a_focal += __shfl_down(a_focal, off);
    a_ent   += __shfl_down(a_ent,   off);
    a_msk   += __shfl_down(a_msk,   off);
    a_uniq  += __shfl_down(a_uniq,  off);
    a_sq    += __shfl_down(a_sq,    off);
  }
  const int wave = tid >> 6;
  if ((tid & 63) == 0) {
    sred[wave][0] = a_focal; sred[wave][1] = a_ent; sred[wave][2] = a_msk;
    sred[wave][3] = a_uniq;  sred[wave][4] = a_sq;
  }
  __syncthreads();
  if (tid < 5) {
    float v = sred[0][tid] + sred[1][tid] + sred[2][tid] + sred[3][tid];
    atomicAdd(&acc[tid], v);
  }
}

__global__ void sudoku_finalize(const float* __restrict__ acc,
                                float* __restrict__ out, float invBG)
{
  float focal = acc[0], ent = acc[1], msum = acc[2], uniq = acc[3], sq = acc[4];
  float inv_m = 1.f / (msum + 1e-8f);
  float ce    = focal * inv_m;
  float entl  = 0.1f * ent * inv_m;
  float uql   = 0.1f * uniq * invBG;
  float rcb   = sq * invBG;    // row+col+box means share denominator B*81
  float constraint = (rcb + entl + uql) * 0.2f;
  out[0] = ce + 0.5f * constraint;
}

extern "C" void kernel_launch(void* const* d_in, const int* in_sizes, int n_in,
                              void* d_out, int out_size, void* d_ws, size_t ws_size,
                              hipStream_t stream)
{
  (void)n_in; (void)out_size; (void)ws_size;
  const float* logits  = (const float*)d_in[0];
  const int*   targets = (const int*)d_in[1];
  const int*   puzzles = (const int*)d_in[2];
  float* out = (float*)d_out;
  float* acc = (float*)d_ws;

  const int B = in_sizes[0] / 729;             // B*9*9*9 logits
  const int numGroups = (B + PB - 1) / PB;

  hipMemsetAsync(acc, 0, 5 * sizeof(float), stream);

  int grid = numGroups < 2048 ? numGroups : 2048;
  sudoku_main<<<grid, THREADS, 0, stream>>>(logits, targets, puzzles, acc, B);

  const float invBG = 1.f / ((float)B * 81.f);
  sudoku_finalize<<<1, 1, 0, stream>>>(acc, out, invBG);
}

// Round 7
// 58.299 us; speedup vs baseline: 1.3795x; 1.0470x over previous
//
#include <hip/hip_runtime.h>

#define THREADS 256
#define PB 3                 // puzzles per block-iteration; 243 phase-A workers
#define NPAIR 5              // f16x2 class-pairs (classes 0..8 + zero pad)
#define COLW 84              // words per (puzzle,pair) column = 3 bands x 28 (16B-aligned)
#define MAXGRID 2048

typedef float f4 __attribute__((ext_vector_type(4)));
typedef f4 f4a4 __attribute__((aligned(4)));        // dword-aligned float4 global loads
typedef __fp16 h2 __attribute__((ext_vector_type(2)));
typedef unsigned int u32;
typedef u32 u32x4 __attribute__((ext_vector_type(4)));

static __device__ __forceinline__ u32 pkrtz(float a, float b) {
  h2 v = __builtin_amdgcn_cvt_pkrtz(a, b);          // v_cvt_pkrtz_f16_f32
  return __builtin_bit_cast(u32, v);
}

__global__ __launch_bounds__(THREADS) void sudoku_main(
    const float* __restrict__ logits,
    const int*   __restrict__ targets,
    const int*   __restrict__ puzzles,
    float* __restrict__ partial,        // [grid][8] per-block partials (no atomics)
    int B)
{
  __shared__ u32 probT[2][PB * NPAIR * COLW];   // packed f16x2 probs, dbuf (10080 B)
  __shared__ float sred[4][5];

  const int tid  = threadIdx.x;
  const int lp   = tid / 81;                    // phase-A local puzzle
  const int cell = tid % 81;
  const bool workerA = tid < 243;
  const int cpad = 28 * (cell / 27) + (cell % 27);   // band-padded column offset
  const int B81  = B * 81;
  const int numGroups = (B + PB - 1) / PB;

  const int lane = tid & 63;
  const int wv   = tid >> 6;
  const int clp  = lane / NPAIR;                // phase-C puzzle (lane<15)
  const int cpr  = lane % NPAIR;                // phase-C class-pair

  float a_focal = 0.f, a_ent = 0.f, a_msk = 0.f, a_uniq = 0.f, a_sq = 0.f;

  // ---- prefetch group 0 ----
  bool vA = workerA && (blockIdx.x * 243 + tid < B81);
  f4 c0{}, c1{}; float c8 = 0.f; int ctg = 0, cpz = 0;
  if (vA) {
    const float* Lp = logits + (size_t)(blockIdx.x * 243 + tid) * 9;
    c0 = *(const f4a4*)Lp; c1 = *(const f4a4*)(Lp + 4); c8 = Lp[8];
    ctg = targets[blockIdx.x * 243 + tid]; cpz = puzzles[blockIdx.x * 243 + tid];
  }

  int it = 0;
  for (int g = blockIdx.x; g < numGroups; g += gridDim.x, ++it) {
    u32* PT = probT[it & 1];

    // ---- phase A: softmax/focal/entropy/top-2 from prefetched regs ----
    if (vA) {
      float l[9];
      l[0]=c0[0]; l[1]=c0[1]; l[2]=c0[2]; l[3]=c0[3];
      l[4]=c1[0]; l[5]=c1[1]; l[6]=c1[2]; l[7]=c1[3]; l[8]=c8;
      int tg = ctg - 1; tg = tg < 0 ? 0 : (tg > 8 ? 8 : tg);

      float t1 = l[0], t2 = -3.0e38f;           // branchless top-2 of logits
#pragma unroll
      for (int i = 1; i < 9; ++i) {
        float hi = fmaxf(t1, l[i]);
        float lo = fminf(t1, l[i]);
        t1 = hi; t2 = fmaxf(t2, lo);
      }
      float e[9], s = 0.f, lsum = 0.f, ltg = l[0];
#pragma unroll
      for (int i = 0; i < 9; ++i) {
        float x  = l[i] - t1;
        float ei = __expf(x);
        e[i] = ei; s += ei;
        lsum = fmaf(ei, x, lsum);
        if (i > 0) ltg = (tg == i) ? l[i] : ltg;
      }
      float inv_s = __builtin_amdgcn_rcpf(s);
      float logs  = __logf(s);
      float lpt   = (ltg - t1) - logs;
      float pt    = __expf(lpt);
      float om    = 1.f - pt;
      float focal = om * om * (-lpt);
      float ent   = logs - lsum * inv_s;
      float gap   = (1.f - __expf(t2 - t1)) * inv_s;
      float uq    = fmaxf(0.f, 1.f - gap);
      float mk    = (cpz == 0) ? 1.f : 0.f;
      a_focal += focal * mk;
      a_ent   += ent * mk;
      a_msk   += mk;
      a_uniq  += uq;                            // uniqueness is unmasked
      float pm = inv_s * mk;

      const int wbase = lp * (NPAIR * COLW) + cpad;   // lanes stride-1: conflict-free
      PT[wbase + 0*COLW] = pkrtz(e[0]*pm, e[1]*pm);
      PT[wbase + 1*COLW] = pkrtz(e[2]*pm, e[3]*pm);
      PT[wbase + 2*COLW] = pkrtz(e[4]*pm, e[5]*pm);
      PT[wbase + 3*COLW] = pkrtz(e[6]*pm, e[7]*pm);
      PT[wbase + 4*COLW] = pkrtz(e[8]*pm, 0.f);
    }

    // ---- prefetch group t+1 BEFORE the barrier ----
    const int gn = g + (int)gridDim.x;
    const bool vAn = workerA && (gn < numGroups) && (gn * 243 + tid < B81);
    f4 n0{}, n1{}; float n8 = 0.f; int ntg = 0, npz = 0;
    if (vAn) {
      const float* Lp = logits + (size_t)(gn * 243 + tid) * 9;
      n0 = *(const f4a4*)Lp; n1 = *(const f4a4*)(Lp + 4); n8 = Lp[8];
      ntg = targets[gn * 243 + tid]; npz = puzzles[gn * 243 + tid];
    }

    __syncthreads();   // only barrier/iter (dbuf covers A(t+1) vs C(t))

    // ---- phase C: rotating wave; lane=(puzzle,pair) sums 2 classes via v_pk_add_f16 ----
    if (wv == (it & 3) && lane < PB * NPAIR && (g * PB + clp) < B) {
      const u32* base = PT + (clp * NPAIR + cpr) * COLW;
      h2 hz; hz[0] = (__fp16)0.f; hz[1] = (__fp16)0.f;
      h2 rs[9], cs[9], bs[9];
#pragma unroll
      for (int u = 0; u < 9; ++u) { rs[u] = hz; cs[u] = hz; bs[u] = hz; }
#pragma unroll
      for (int b = 0; b < 3; ++b) {             // band = 3 rows = 27 cells (+1 pad word)
        u32x4 w[7];
#pragma unroll
        for (int q = 0; q < 7; ++q) w[q] = *(const u32x4*)(base + b * 28 + q * 4);
#pragma unroll
        for (int j = 0; j < 27; ++j) {          // all indices compile-time
          h2 v = __builtin_bit_cast(h2, w[j >> 2][j & 3]);
          rs[3 * b + j / 9]       += v;
          cs[j % 9]               += v;
          bs[3 * b + (j % 9) / 3] += v;
        }
      }
      const float hiw = (cpr == NPAIR - 1) ? 0.f : 1.f;   // pad class excluded
      float sq = 0.f;
#pragma unroll
      for (int u = 0; u < 9; ++u) {
        float x;
        x = (float)rs[u][0] - 1.f; sq = fmaf(x, x, sq);
        x = (float)cs[u][0] - 1.f; sq = fmaf(x, x, sq);
        x = (float)bs[u][0] - 1.f; sq = fmaf(x, x, sq);
        x = (float)rs[u][1] - 1.f; sq = fmaf(hiw * x, x, sq);
        x = (float)cs[u][1] - 1.f; sq = fmaf(hiw * x, x, sq);
        x = (float)bs[u][1] - 1.f; sq = fmaf(hiw * x, x, sq);
      }
      a_sq += sq;
    }

    vA = vAn; c0 = n0; c1 = n1; c8 = n8; ctg = ntg; cpz = npz;
  }

  // ---- wave + block reduction, per-block partial store (NO atomics) ----
#pragma unroll
  for (int off = 32; off > 0; off >>= 1) {
    a_focal += __shfl_down(a_focal, off);
    a_ent   += __shfl_down(a_ent,   off);
    a_msk   += __shfl_down(a_msk,   off);
    a_uniq  += __shfl_down(a_uniq,  off);
    a_sq    += __shfl_down(a_sq,    off);
  }
  if (lane == 0) {
    sred[wv][0] = a_focal; sred[wv][1] = a_ent; sred[wv][2] = a_msk;
    sred[wv][3] = a_uniq;  sred[wv][4] = a_sq;
  }
  __syncthreads();
  if (tid < 5) {
    float v = sred[0][tid] + sred[1][tid] + sred[2][tid] + sred[3][tid];
    partial[(size_t)blockIdx.x * 8 + tid] = v;
  }
}

__global__ __launch_bounds__(256) void sudoku_finalize(
    const float* __restrict__ partial, float* __restrict__ out,
    int nblk, float invBG)
{
  __shared__ float sb[4][5];
  const int tid = threadIdx.x;
  float s[5] = {0.f, 0.f, 0.f, 0.f, 0.f};
  for (int b = tid; b < nblk; b += 256) {
    const float* row = partial + (size_t)b * 8;
#pragma unroll
    for (int u = 0; u < 5; ++u) s[u] += row[u];
  }
#pragma unroll
  for (int off = 32; off > 0; off >>= 1)
#pragma unroll
    for (int u = 0; u < 5; ++u) s[u] += __shfl_down(s[u], off);
  const int wv = tid >> 6, lane = tid & 63;
  if (lane == 0) {
#pragma unroll
    for (int u = 0; u < 5; ++u) sb[wv][u] = s[u];
  }
  __syncthreads();
  if (tid == 0) {
    float focal = sb[0][0] + sb[1][0] + sb[2][0] + sb[3][0];
    float ent   = sb[0][1] + sb[1][1] + sb[2][1] + sb[3][1];
    float msum  = sb[0][2] + sb[1][2] + sb[2][2] + sb[3][2];
    float uniq  = sb[0][3] + sb[1][3] + sb[2][3] + sb[3][3];
    float sq    = sb[0][4] + sb[1][4] + sb[2][4] + sb[3][4];
    float inv_m = 1.f / (msum + 1e-8f);
    float ce    = focal * inv_m;
    float entl  = 0.1f * ent * inv_m;
    float uql   = 0.1f * uniq * invBG;
    float rcb   = sq * invBG;     // row+col+box means share denominator B*81
    float constraint = (rcb + entl + uql) * 0.2f;
    out[0] = ce + 0.5f * constraint;
  }
}

extern "C" void kernel_launch(void* const* d_in, const int* in_sizes, int n_in,
                              void* d_out, int out_size, void* d_ws, size_t ws_size,
                              hipStream_t stream)
{
  (void)n_in; (void)out_size; (void)ws_size;
  const float* logits  = (const float*)d_in[0];
  const int*   targets = (const int*)d_in[1];
  const int*   puzzles = (const int*)d_in[2];
  float* out = (float*)d_out;
  float* partial = (float*)d_ws;

  const int B = in_sizes[0] / 729;              // B*9*9*9 logits
  const int numGroups = (B + PB - 1) / PB;
  int grid = numGroups < MAXGRID ? numGroups : MAXGRID;

  sudoku_main<<<grid, THREADS, 0, stream>>>(logits, targets, puzzles, partial, B);

  const float invBG = 1.f / ((float)B * 81.f);
  sudoku_finalize<<<1, 256, 0, stream>>>(partial, out, grid, invBG);
}

// Round 8
// 57.203 us; speedup vs baseline: 1.4059x; 1.0192x over previous
//
#include <hip/hip_runtime.h>

#define THREADS 256
#define PB 12                        // puzzles per block (no loop)
#define CELLS_PB (PB * 81)           // 972 cells
#define WORKERS 243                  // lanes; 4 consecutive cells each
#define TOTW (CELLS_PB * 9)          // 8748 words staged

typedef float f4 __attribute__((ext_vector_type(4)));
typedef __fp16 h2 __attribute__((ext_vector_type(2)));
typedef unsigned int u32;
typedef int i4 __attribute__((ext_vector_type(4)));

static __device__ __forceinline__ u32 pkrtz(float a, float b) {
  h2 v = __builtin_amdgcn_cvt_pkrtz(a, b);     // v_cvt_pkrtz_f16_f32
  return __builtin_bit_cast(u32, v);
}

__global__ __launch_bounds__(THREADS) void sudoku_main(
    const float* __restrict__ logits,
    const int*   __restrict__ targets,
    const int*   __restrict__ puzzles,
    float* __restrict__ partial,      // transposed [5][ngrid]
    int B, int ngrid)
{
  __shared__ float buf[TOTW];         // staged logits f32 -> probs f16x2 in place (35 KB)
  __shared__ float sred[4][5];

  const int tid = threadIdx.x;
  const int g   = blockIdx.x;
  const long totalCells = (long)B * 81;

  float a_focal=0.f, a_ent=0.f, a_msk=0.f, a_uniq=0.f, a_sq=0.f;

  // ---- stage logits: 243 lanes x 9 rounds of dense float4 (fully coalesced) ----
  if (tid < WORKERS) {
    const size_t gbase4 = (size_t)g * (TOTW / 4);          // 2187 f4 per group
    const size_t lim4   = (size_t)(totalCells * 9 / 4);
    const f4* src = (const f4*)logits;
#pragma unroll
    for (int r = 0; r < 9; ++r) {
      size_t idx = gbase4 + r * WORKERS + tid;
      if (idx < lim4) ((f4*)buf)[r * WORKERS + tid] = src[idx];
    }
  }

  // ---- per-lane int loads: 4 cells as one int4 each (dense lines) ----
  const long cell0 = (long)g * CELLS_PB + 4 * tid;
  const bool vA = (tid < WORKERS) && (cell0 < totalCells);
  i4 tg4{}, pz4{};
  if (vA) {
    tg4 = *(const i4*)(targets + cell0);
    pz4 = *(const i4*)(puzzles + cell0);
  }
  __syncthreads();

  // ---- phase A: read own 144B slice (9x b128, conflict-free), 4 cells in regs ----
  if (vA) {
    f4 s[9];
#pragma unroll
    for (int q = 0; q < 9; ++q) s[q] = ((const f4*)buf)[tid * 9 + q];

#pragma unroll
    for (int k = 0; k < 4; ++k) {
      float l[9];
#pragma unroll
      for (int i = 0; i < 9; ++i) { const int w = 9 * k + i; l[i] = s[w >> 2][w & 3]; }
      int tg = tg4[k] - 1; tg = tg < 0 ? 0 : (tg > 8 ? 8 : tg);

      float t1 = l[0], t2 = -3.0e38f;            // branchless top-2 of logits
#pragma unroll
      for (int i = 1; i < 9; ++i) {
        float hi = fmaxf(t1, l[i]);
        float lo = fminf(t1, l[i]);
        t1 = hi; t2 = fmaxf(t2, lo);
      }
      float e[9], ssum = 0.f, lsum = 0.f, ltg = l[0];
#pragma unroll
      for (int i = 0; i < 9; ++i) {
        float x  = l[i] - t1;
        float ei = __expf(x);
        e[i] = ei; ssum += ei;
        lsum = fmaf(ei, x, lsum);
        if (i > 0) ltg = (tg == i) ? l[i] : ltg;
      }
      float inv_s = __builtin_amdgcn_rcpf(ssum);
      float logs  = __logf(ssum);
      float lpt   = (ltg - t1) - logs;
      float pt    = __expf(lpt);
      float om    = 1.f - pt;
      float focal = om * om * (-lpt);
      float ent   = logs - lsum * inv_s;
      float gap   = (1.f - __expf(t2 - t1)) * inv_s;
      float uq    = fmaxf(0.f, 1.f - gap);
      float mk    = (pz4[k] == 0) ? 1.f : 0.f;
      a_focal += focal * mk;
      a_ent   += ent * mk;
      a_msk   += mk;
      a_uniq  += uq;                             // uniqueness is unmasked
      float pm = inv_s * mk;

      // overwrite own slice with f16x2 prob-pairs: [cell][9] words, b128-friendly
      u32* pw = (u32*)buf + (size_t)(4 * tid + k) * 9;
      pw[0] = pkrtz(e[0] * pm, e[1] * pm);
      pw[1] = pkrtz(e[2] * pm, e[3] * pm);
      pw[2] = pkrtz(e[4] * pm, e[5] * pm);
      pw[3] = pkrtz(e[6] * pm, e[7] * pm);
      pw[4] = pkrtz(e[8] * pm, 0.f);
    }
  }
  __syncthreads();

  // ---- phase C: 60 lanes, one per (puzzle, class-pair); 81 b32 reads each ----
  if (tid < PB * 5) {
    const int pz = tid / 5, pr = tid - 5 * pz;
    if ((long)g * PB + pz < B) {
      const u32* cb = (const u32*)buf;
      h2 hz; hz[0] = (__fp16)0.f; hz[1] = (__fp16)0.f;
      h2 rs[9], cs[9], bs[9];
#pragma unroll
      for (int u = 0; u < 9; ++u) { rs[u] = hz; cs[u] = hz; bs[u] = hz; }
      const int base = pz * 729 + pr;            // word (pz*81+j)*9 + pr
#pragma unroll
      for (int j = 0; j < 81; ++j) {
        h2 v = __builtin_bit_cast(h2, cb[base + 9 * j]);
        rs[j / 9]                    += v;
        cs[j % 9]                    += v;
        bs[(j / 27) * 3 + (j % 9) / 3] += v;
      }
      const float hiw = (pr == 4) ? 0.f : 1.f;   // pad class excluded
      float sq = 0.f;
#pragma unroll
      for (int u = 0; u < 9; ++u) {
        float x;
        x = (float)rs[u][0] - 1.f; sq = fmaf(x, x, sq);
        x = (float)cs[u][0] - 1.f; sq = fmaf(x, x, sq);
        x = (float)bs[u][0] - 1.f; sq = fmaf(x, x, sq);
        x = (float)rs[u][1] - 1.f; sq = fmaf(hiw * x, x, sq);
        x = (float)cs[u][1] - 1.f; sq = fmaf(hiw * x, x, sq);
        x = (float)bs[u][1] - 1.f; sq = fmaf(hiw * x, x, sq);
      }
      a_sq += sq;
    }
  }

  // ---- wave + block reduction, transposed partial store (no atomics) ----
#pragma unroll
  for (int off = 32; off > 0; off >>= 1) {
    a_focal += __shfl_down(a_focal, off);
    a_ent   += __shfl_down(a_ent,   off);
    a_msk   += __shfl_down(a_msk,   off);
    a_uniq  += __shfl_down(a_uniq,  off);
    a_sq    += __shfl_down(a_sq,    off);
  }
  const int wv = tid >> 6, lane = tid & 63;
  if (lane == 0) {
    sred[wv][0] = a_focal; sred[wv][1] = a_ent; sred[wv][2] = a_msk;
    sred[wv][3] = a_uniq;  sred[wv][4] = a_sq;
  }
  __syncthreads();
  if (tid < 5) {
    float v = sred[0][tid] + sred[1][tid] + sred[2][tid] + sred[3][tid];
    partial[(size_t)tid * ngrid + g] = v;
  }
}

__global__ __launch_bounds__(1024) void sudoku_finalize(
    const float* __restrict__ partial, float* __restrict__ out,
    int ngrid, float invBG)
{
  __shared__ float sb[16][5];
  const int tid = threadIdx.x;
  float s[5] = {0.f, 0.f, 0.f, 0.f, 0.f};
  for (int b = tid; b < ngrid; b += 1024) {
#pragma unroll
    for (int u = 0; u < 5; ++u) s[u] += partial[(size_t)u * ngrid + b];   // coalesced
  }
#pragma unroll
  for (int off = 32; off > 0; off >>= 1)
#pragma unroll
    for (int u = 0; u < 5; ++u) s[u] += __shfl_down(s[u], off);
  const int wv = tid >> 6, lane = tid & 63;
  if (lane == 0) {
#pragma unroll
    for (int u = 0; u < 5; ++u) sb[wv][u] = s[u];
  }
  __syncthreads();
  if (tid == 0) {
    float focal = 0.f, ent = 0.f, msum = 0.f, uniq = 0.f, sq = 0.f;
#pragma unroll
    for (int w = 0; w < 16; ++w) {
      focal += sb[w][0]; ent += sb[w][1]; msum += sb[w][2];
      uniq  += sb[w][3]; sq  += sb[w][4];
    }
    float inv_m = 1.f / (msum + 1e-8f);
    float ce    = focal * inv_m;
    float entl  = 0.1f * ent * inv_m;
    float uql   = 0.1f * uniq * invBG;
    float rcb   = sq * invBG;        // row+col+box means share denominator B*81
    float constraint = (rcb + entl + uql) * 0.2f;
    out[0] = ce + 0.5f * constraint;
  }
}

extern "C" void kernel_launch(void* const* d_in, const int* in_sizes, int n_in,
                              void* d_out, int out_size, void* d_ws, size_t ws_size,
                              hipStream_t stream)
{
  (void)n_in; (void)out_size; (void)ws_size;
  const float* logits  = (const float*)d_in[0];
  const int*   targets = (const int*)d_in[1];
  const int*   puzzles = (const int*)d_in[2];
  float* out = (float*)d_out;
  float* partial = (float*)d_ws;

  const int B = in_sizes[0] / 729;               // B*9*9*9 logits
  const long totalCells = (long)B * 81;
  const int ngrid = (int)((totalCells + CELLS_PB - 1) / CELLS_PB);   // 5462

  sudoku_main<<<ngrid, THREADS, 0, stream>>>(logits, targets, puzzles, partial, B, ngrid);

  const float invBG = 1.f / ((float)B * 81.f);
  sudoku_finalize<<<1, 1024, 0, stream>>>(partial, out, ngrid, invBG);
}